// Round 4
// baseline (86.636 us; speedup 1.0000x reference)
//
#include <hip/hip_runtime.h>
#include <stdint.h>

#define B_N   32
#define T_N   8192
#define D_N   256
#define CTX_N 128
#define TB    32                      /* rows per chunk           */
#define CPB   4                       /* chunks per block         */
#define ROWS_PB (TB*CPB)              /* 128 rows per block       */
#define BLK_PER_B (T_N/ROWS_PB)       /* 64 blocks per batch      */
#define NBLOCKS (B_N*BLK_PER_B)       /* 2048                     */
#define XP    264                     /* bf16 pitch (528 B rows)  */

typedef unsigned short u16;
typedef unsigned int   u32;
typedef __attribute__((ext_vector_type(8))) short bf16x8;
typedef __attribute__((ext_vector_type(8))) unsigned short u16x8;
typedef __attribute__((ext_vector_type(4))) float f32x4;

__device__ __forceinline__ u16 f2bf(float f) {          /* RNE float->bf16 */
  u32 u = __float_as_uint(f);
  return (u16)((u + 0x7FFFu + ((u >> 16) & 1u)) >> 16);
}
__device__ __forceinline__ float fast_tanh(float x) {
  float e = __expf(2.0f * x);
  return (e - 1.0f) * __builtin_amdgcn_rcpf(e + 1.0f);
}
/* 16-lane rotate-reduce on the VALU (DPP row_ror), not the DS pipe */
__device__ __forceinline__ float rr16_add(float v) {
  int x;
  x = __builtin_amdgcn_update_dpp(0, __float_as_int(v), 0x128, 0xF, 0xF, true); v += __int_as_float(x);
  x = __builtin_amdgcn_update_dpp(0, __float_as_int(v), 0x124, 0xF, 0xF, true); v += __int_as_float(x);
  x = __builtin_amdgcn_update_dpp(0, __float_as_int(v), 0x122, 0xF, 0xF, true); v += __int_as_float(x);
  x = __builtin_amdgcn_update_dpp(0, __float_as_int(v), 0x121, 0xF, 0xF, true); v += __int_as_float(x);
  return v;
}

/* ---------- kernel 0: W (D x CTX fp32) -> Wt (CTX x D bf16) ---------- */
__global__ void prep_w(const float* __restrict__ W, u16* __restrict__ Wt) {
  int c = blockIdx.x;    /* ctx */
  int d = threadIdx.x;   /* dim */
  Wt[c * D_N + d] = f2bf(W[d * CTX_N + c]);
}

/* ---------- kernel 1: fused scores+softmax+wsum ---------- */
__global__ __launch_bounds__(512, 4)
void attn_main(const float* __restrict__ X, const u16* __restrict__ Wt,
               const float* __restrict__ u,
               float* __restrict__ blk_o, float* __restrict__ blk_l) {
  __shared__ u16   Xl[2][TB][XP];     /* 33792 B, double-buffered bf16 X  */
  __shared__ float s_part[8][TB];     /* per-wave score partials          */
  __shared__ float l_part[TB];

  const int tid = threadIdx.x;
  const int w   = tid >> 6;           /* wave 0..7: ctx cols w*16..+15 */
  const int l   = tid & 63;
  const int l15 = l & 15;
  const int lg  = l >> 4;

  const int blk  = blockIdx.x;
  const int b    = blk >> 6;
  const int rowB = (blk & (BLK_PER_B - 1)) * ROWS_PB;
  const float* Xbase = X + ((size_t)b * T_N + rowB) * D_N;

  /* W^T fragments in registers: 8 x bf16x8 = 32 VGPRs */
  bf16x8 bw[8];
  {
    const u16* wp = Wt + (w * 16 + l15) * D_N + lg * 8;
    #pragma unroll
    for (int kk = 0; kk < 8; ++kk) bw[kk] = *(const bf16x8*)(wp + kk * 32);
  }
  const float uc = u[w * 16 + l15];

  /* staging/wsum map: thread = (row srow, 16-float segment scol) */
  const int srow = tid >> 4;          /* 0..31 */
  const int scol = (tid & 15) << 4;   /* 0..240 */
  const float* Xrow = Xbase + (size_t)srow * D_N + scol;

  float4 pa0, pa1, pa2, pa3, pb0, pb1, pb2, pb3;
  pa0 = ((const float4*)Xrow)[0]; pa1 = ((const float4*)Xrow)[1];
  pa2 = ((const float4*)Xrow)[2]; pa3 = ((const float4*)Xrow)[3];

  float4 o0 = {0,0,0,0}, o1 = {0,0,0,0}, o2 = {0,0,0,0}, o3 = {0,0,0,0};
  float l_run = 0.f;

#define CHUNK(c, P0,P1,P2,P3, Q0,Q1,Q2,Q3)                                    \
  {                                                                           \
    const int cur = (c) & 1;                                                  \
    u16x8 s0, s1;                                                             \
    s0[0]=f2bf(P0.x); s0[1]=f2bf(P0.y); s0[2]=f2bf(P0.z); s0[3]=f2bf(P0.w);   \
    s0[4]=f2bf(P1.x); s0[5]=f2bf(P1.y); s0[6]=f2bf(P1.z); s0[7]=f2bf(P1.w);   \
    s1[0]=f2bf(P2.x); s1[1]=f2bf(P2.y); s1[2]=f2bf(P2.z); s1[3]=f2bf(P2.w);   \
    s1[4]=f2bf(P3.x); s1[5]=f2bf(P3.y); s1[6]=f2bf(P3.z); s1[7]=f2bf(P3.w);   \
    *(u16x8*)&Xl[cur][srow][scol]     = s0;                                   \
    *(u16x8*)&Xl[cur][srow][scol + 8] = s1;                                   \
    if ((c) + 1 < CPB) {            /* early global issue for c+1 */          \
      const float* sp_ = Xrow + (size_t)((c) + 1) * TB * D_N;                 \
      Q0 = ((const float4*)sp_)[0]; Q1 = ((const float4*)sp_)[1];             \
      Q2 = ((const float4*)sp_)[2]; Q3 = ((const float4*)sp_)[3];             \
    }                                                                         \
    asm volatile("s_waitcnt lgkmcnt(0)" ::: "memory");                        \
    __builtin_amdgcn_s_barrier();          /* A: buf[cur] ready */            \
    asm volatile("" ::: "memory");                                            \
    const u16* Xc = &Xl[cur][0][0];                                           \
    f32x4 acc0 = {0,0,0,0}, acc1 = {0,0,0,0};                                 \
    _Pragma("unroll")                                                         \
    for (int kk = 0; kk < 8; ++kk) {                                          \
      bf16x8 a0 = *(const bf16x8*)(Xc + l15 * XP + kk * 32 + lg * 8);         \
      bf16x8 a1 = *(const bf16x8*)(Xc + (16 + l15) * XP + kk * 32 + lg * 8);  \
      acc0 = __builtin_amdgcn_mfma_f32_16x16x32_bf16(a0, bw[kk], acc0,0,0,0); \
      acc1 = __builtin_amdgcn_mfma_f32_16x16x32_bf16(a1, bw[kk], acc1,0,0,0); \
    }                                                                         \
    _Pragma("unroll")                                                         \
    for (int r = 0; r < 4; ++r) {                                             \
      float v0 = rr16_add(uc * fast_tanh(acc0[r]));                           \
      float v1 = rr16_add(uc * fast_tanh(acc1[r]));                           \
      if (l15 == 0) {                                                         \
        s_part[w][lg * 4 + r]      = v0;                                      \
        s_part[w][16 + lg * 4 + r] = v1;                                      \
      }                                                                       \
    }                                                                         \
    asm volatile("s_waitcnt lgkmcnt(0)" ::: "memory");                        \
    __builtin_amdgcn_s_barrier();          /* B: s_part ready */              \
    asm volatile("" ::: "memory");                                            \
    float st = s_part[0][srow] + s_part[1][srow] + s_part[2][srow]            \
             + s_part[3][srow] + s_part[4][srow] + s_part[5][srow]            \
             + s_part[6][srow] + s_part[7][srow];                             \
    float p = __expf(st);                                                     \
    if ((tid & 15) == 0) l_run += p;                                          \
    o0.x += p*P0.x; o0.y += p*P0.y; o0.z += p*P0.z; o0.w += p*P0.w;           \
    o1.x += p*P1.x; o1.y += p*P1.y; o1.z += p*P1.z; o1.w += p*P1.w;           \
    o2.x += p*P2.x; o2.y += p*P2.y; o2.z += p*P2.z; o2.w += p*P2.w;           \
    o3.x += p*P3.x; o3.y += p*P3.y; o3.z += p*P3.z; o3.w += p*P3.w;           \
  }

  CHUNK(0, pa0,pa1,pa2,pa3, pb0,pb1,pb2,pb3)
  CHUNK(1, pb0,pb1,pb2,pb3, pa0,pa1,pa2,pa3)
  CHUNK(2, pa0,pa1,pa2,pa3, pb0,pb1,pb2,pb3)
  CHUNK(3, pb0,pb1,pb2,pb3, pa0,pa1,pa2,pa3)
#undef CHUNK

  /* ---- block combine: sum o over the 32 srow-threads per segment ---- */
  __syncthreads();
  float* comb = (float*)&Xl[0][0][0];   /* 32 rows x pitch 260 = 33280 B */
  {
    float* cp = comb + srow * 260 + scol;
    *(float4*)(cp + 0)  = o0;
    *(float4*)(cp + 4)  = o1;
    *(float4*)(cp + 8)  = o2;
    *(float4*)(cp + 12) = o3;
  }
  if ((tid & 15) == 0) l_part[srow] = l_run;
  __syncthreads();
  if (tid < 256) {
    float o = 0.f;
    #pragma unroll
    for (int s = 0; s < 32; ++s) o += comb[s * 260 + tid];
    blk_o[(size_t)blk * D_N + tid] = o;
  }
  if (tid == 0) {
    float L = 0.f;
    #pragma unroll
    for (int s = 0; s < 32; ++s) L += l_part[s];
    blk_l[blk] = L;
  }
}

/* ---------- kernel 2: combine 64 block-partials per batch ---------- */
__global__ __launch_bounds__(256)
void finalize(const float* __restrict__ blk_o, const float* __restrict__ blk_l,
              float* __restrict__ out) {
  const int b = blockIdx.x, d = threadIdx.x;
  float o = 0.f, L = 0.f;
  for (int i = 0; i < BLK_PER_B; ++i) {
    o += blk_o[(size_t)(b * BLK_PER_B + i) * D_N + d];
    L += blk_l[b * BLK_PER_B + i];
  }
  out[b * D_N + d] = o / L;
}

/* ---------- launch ---------- */
extern "C" void kernel_launch(void* const* d_in, const int* in_sizes, int n_in,
                              void* d_out, int out_size, void* d_ws, size_t ws_size,
                              hipStream_t stream) {
  const float* X = (const float*)d_in[0];
  const float* W = (const float*)d_in[1];
  const float* u = (const float*)d_in[2];
  float* out = (float*)d_out;

  u16*   Wt    = (u16*)d_ws;                                        /* 64 KiB */
  float* blk_o = (float*)((char*)d_ws + 65536);                     /* 2 MiB  */
  float* blk_l = (float*)((char*)d_ws + 65536 + (size_t)NBLOCKS * D_N * 4);

  prep_w<<<CTX_N, D_N, 0, stream>>>(W, Wt);
  attn_main<<<NBLOCKS, 512, 0, stream>>>(X, Wt, u, blk_o, blk_l);
  finalize<<<B_N, 256, 0, stream>>>(blk_o, blk_l, out);
}